// Round 4
// baseline (46954.947 us; speedup 1.0000x reference)
//
#include <hip/hip_runtime.h>
#include <hip/hip_cooperative_groups.h>

namespace cg = cooperative_groups;

#define B    1024
#define T    256
#define NBLK 256
#define NTHR 512
#define EPS  1e-5f

// ---- ws float offsets ----
#define WS_H1X 0                    // [256][B] h1(t) exchange
#define WS_H2X 262144               // [256][B]
#define WS_H3X 524288               // [32][B]
#define WS_ST  557056               // [T][1088]: st1 256*2 | st2 256*2 | st3 32*2

// ---- LDS float offsets (all dynamic) ----
#define ZX    0        // z buffer [16][260] (z1/z2) / xrow alias [16][132]
#define H1F   4160     // [16][260] raw h1(t) b-major (pitch 260)
#define H2F   8320     // [16][260] raw h2(t)
#define H3F   12480    // [16][40]  raw h3(t-1)
#define C1O   13120    // [64][16]
#define C2O   14144    // [64][16]
#define C3O   15168    // [8][16]
#define GBUF  15296    // [2 par][8 kq][16 r][16 b]
#define G3BUF 19392    // [4 kq][32 r][16 b]
#define SA    21440    // [256]
#define SD    21696    // [256]
#define SB1   21952    // [64][4]
#define SB2   22208    // [64][4]
#define SB3   22464    // [8][4]
#define SWH   22496    // Wl(64) Wl2(4) bl(2) bl2(2)
#define WST   22568    // [2][8192] weight staging (xor-swizzled rows)
#define LDS_FLOATS 38952   // 155,808 B

__device__ __forceinline__ float fsigmoid(float v) { return 1.f / (1.f + __expf(-v)); }
__device__ __forceinline__ float ftanh(float v)    { return 1.f - 2.f / (__expf(2.f * v) + 1.f); }

__device__ __forceinline__ float lstm_point(float gi, float gf, float gg, float go, float& c) {
    const float i = fsigmoid(gi), f = fsigmoid(gf), g = ftanh(gg), o = fsigmoid(go);
    c = f * c + i * g;
    return o * ftanh(c);
}

__device__ __forceinline__ void gld16(const float* g, float* l) {
    __builtin_amdgcn_global_load_lds(
        (const __attribute__((address_space(1))) unsigned int*)g,
        (__attribute__((address_space(3))) unsigned int*)l, 16, 0, 0);
}

__device__ __forceinline__ float dot4(const float4 w, const float4 a) {
    return w.x * a.x + w.y * a.y + w.z * a.z + w.w * a.w;
}

__global__ void __launch_bounds__(NTHR, 1) cryptonet_kernel(
    const float* __restrict__ x,
    const float* __restrict__ Wih1, const float* __restrict__ Whh1,
    const float* __restrict__ bih1, const float* __restrict__ bhh1,
    const float* __restrict__ g1v,  const float* __restrict__ b1v,
    const float* __restrict__ Wih2, const float* __restrict__ Whh2,
    const float* __restrict__ bih2, const float* __restrict__ bhh2,
    const float* __restrict__ g2v,  const float* __restrict__ b2v,
    const float* __restrict__ Wih3, const float* __restrict__ Whh3,
    const float* __restrict__ bih3, const float* __restrict__ bhh3,
    const float* __restrict__ g3v,  const float* __restrict__ b3v,
    const float* __restrict__ Wl,   const float* __restrict__ bl,
    const float* __restrict__ Wl2,  const float* __restrict__ bl2,
    float* __restrict__ out, float* __restrict__ ws)
{
    cg::grid_group grid = cg::this_grid();
    const int tid = threadIdx.x;
    const int blk = blockIdx.x;
    const int CQ = blk >> 6;          // channel quarter 0..3 (partners 64 apart -> same XCD)
    const int BG = blk & 63;          // batch group: rows BG*16 .. +16
    const int wv = tid >> 6;
    const int lane = tid & 63;

    extern __shared__ float smem[];

    // ---- stage a 16-gate-row weight chunk (phases 1/2), xor-swizzled ----
    auto stage12 = [&](int ci, int par, int phase) {
        const int spr = (phase == 1) ? 96 : 128;       // 16B slots per row
        const int slots = 16 * spr;
        float* dst = smem + WST + par * 8192;
        #pragma unroll
        for (int rnd = 0; rnd < 4; ++rnd) {
            const int base = rnd * 512 + wv * 64;
            if (base < slots) {
                const int p = base + lane;
                const int r = p / spr;
                const int sl = (p - r * spr) ^ (r & 7);
                const int f = sl * 4;
                const int j = (r >> 2) * 256 + CQ * 64 + ci * 4 + (r & 3);
                const float* src;
                if (phase == 1)
                    src = (f < 128) ? (Wih1 + (size_t)j * 128 + f)
                                    : (Whh1 + (size_t)j * 256 + (f - 128));
                else
                    src = (f < 256) ? (Wih2 + (size_t)j * 256 + f)
                                    : (Whh2 + (size_t)j * 256 + (f - 256));
                gld16(src, dst + base * 4);
            }
        }
    };
    // ---- stage whole W3 slice (32 rows x 288) ----
    auto stage3 = [&]() {
        float* dst = smem + WST;
        #pragma unroll
        for (int rnd = 0; rnd < 5; ++rnd) {
            const int base = rnd * 512 + wv * 64;
            if (base < 2304) {
                const int p = base + lane;
                const int r = p / 72;
                const int sl = (p - r * 72) ^ (r & 7);
                const int f = sl * 4;
                const int j = (r >> 3) * 32 + CQ * 8 + (r & 7);
                const float* src = (f < 256) ? (Wih3 + (size_t)j * 256 + f)
                                             : (Whh3 + (size_t)j * 32 + (f - 256));
                gld16(src, dst + base * 4);
            }
        }
    };

    // ---- compute one chunk (phases 1/2): thread = (kq=wave, ch4, b), 4 gate accs ----
    auto compute12 = [&](int ci, int par, int phase) {
        const int kq = wv;
        const int ch4 = (tid >> 4) & 3;
        const int b = tid & 15;
        const int spr = (phase == 1) ? 96 : 128;
        const int kn = (phase == 1) ? 48 : 64;
        const int k0 = kq * kn;
        const float* wbase = smem + WST + par * 8192;
        int alen;
        const float *actA, *actB;
        if (phase == 1) {
            int xl = 128 - k0; if (xl < 0) xl = 0; if (xl > kn) xl = kn;
            alen = xl >> 2;
            actA = smem + ZX + b * 132 + k0;
            actB = smem + H1F + b * 260 + (k0 + (alen << 2) - 128);
        } else {
            int zl = 256 - k0; if (zl < 0) zl = 0; if (zl > kn) zl = kn;
            alen = zl >> 2;
            actA = smem + ZX + b * 260 + k0;
            actB = smem + H2F + b * 260 + (k0 + (alen << 2) - 256);
        }
        const int nf4 = kn >> 2;
        const int s0 = k0 >> 2;
        float acc0 = 0.f, acc1 = 0.f, acc2 = 0.f, acc3 = 0.f;
        #pragma unroll 4
        for (int i = 0; i < nf4; ++i) {
            const float* ap = (i < alen) ? (actA + 4 * i) : (actB + 4 * (i - alen));
            const float4 a = *(const float4*)ap;
            const int sl = s0 + i;
            {   const int r = 0 * 4 + ch4;
                const float4 w = *(const float4*)(wbase + (r * spr + (sl ^ (r & 7))) * 4);
                acc0 += dot4(w, a); }
            {   const int r = 1 * 4 + ch4;
                const float4 w = *(const float4*)(wbase + (r * spr + (sl ^ (r & 7))) * 4);
                acc1 += dot4(w, a); }
            {   const int r = 2 * 4 + ch4;
                const float4 w = *(const float4*)(wbase + (r * spr + (sl ^ (r & 7))) * 4);
                acc2 += dot4(w, a); }
            {   const int r = 3 * 4 + ch4;
                const float4 w = *(const float4*)(wbase + (r * spr + (sl ^ (r & 7))) * 4);
                acc3 += dot4(w, a); }
        }
        smem[GBUF + ((par * 8 + kq) * 16 + 0 * 4 + ch4) * 16 + b] = acc0;
        smem[GBUF + ((par * 8 + kq) * 16 + 1 * 4 + ch4) * 16 + b] = acc1;
        smem[GBUF + ((par * 8 + kq) * 16 + 2 * 4 + ch4) * 16 + b] = acc2;
        smem[GBUF + ((par * 8 + kq) * 16 + 3 * 4 + ch4) * 16 + b] = acc3;
    };

    // ---- pointwise LSTM for one chunk's 4 channels (tid < 64) ----
    auto point12 = [&](int ci, int par, int phase, int tstep) {
        const int ch4 = tid >> 4;
        const int b = tid & 15;
        const int ch = ci * 4 + ch4;     // cq-local 0..63
        float gg[4];
        #pragma unroll
        for (int g = 0; g < 4; ++g) {
            float s = smem[(phase == 1 ? SB1 : SB2) + ch * 4 + g];
            #pragma unroll
            for (int kq = 0; kq < 8; ++kq)
                s += smem[GBUF + ((par * 8 + kq) * 16 + g * 4 + ch4) * 16 + b];
            gg[g] = s;
        }
        float* cp = smem + (phase == 1 ? C1O : C2O) + ch * 16 + b;
        float c = *cp;
        const float h = lstm_point(gg[0], gg[1], gg[2], gg[3], c);
        *cp = c;
        ws[(phase == 1 ? WS_H1X : WS_H2X) + (size_t)(CQ * 64 + ch) * B + BG * 16 + b] = h;
        float s = h, q = h * h;
        #pragma unroll
        for (int off = 1; off < 16; off <<= 1) {
            s += __shfl_xor(s, off, 64);
            q += __shfl_xor(q, off, 64);
        }
        if (b == 0) {
            float* st = ws + WS_ST + (size_t)tstep * 1088 + (phase == 1 ? 0 : 512)
                        + (size_t)(CQ * 64 + ch) * 2;
            atomicAdd(st, s);
            atomicAdd(st + 1, q);
        }
    };

    // ---- BN a/d from accumulated stats ----
    auto bn_ad = [&](const float* stbase, const float* gv, const float* bv, int n) {
        if (tid < n) {
            const float s = stbase[tid * 2], q = stbase[tid * 2 + 1];
            const float mu = s * (1.f / B);
            const float var = q * (1.f / B) - mu * mu;
            const float a = gv[tid] * rsqrtf(var + EPS);
            smem[SA + tid] = a;
            smem[SD + tid] = bv[tid] - mu * a;
        }
    };

    // ---- assemble full h (raw) + z (folded) from exchange buffer ----
    auto assemble = [&](const float* hx, int h_lds) {
        const int ch = tid >> 1;
        const int j0 = (tid & 1) * 8;
        const float* src = hx + (size_t)ch * B + BG * 16 + j0;
        const float a = smem[SA + ch], d = smem[SD + ch];
        #pragma unroll
        for (int jj = 0; jj < 8; ++jj) {
            const float h = src[jj];
            smem[h_lds + (j0 + jj) * 260 + ch] = h;
            smem[ZX + (j0 + jj) * 260 + ch] = a * h + d;
        }
    };

    // ---- L3 gate compute: thread = (kq 0..3, ch 0..7, b) ----
    auto compute3 = [&]() {
        const int kq = tid >> 7;
        const int ch = (tid >> 4) & 7;
        const int b = tid & 15;
        const int k0 = kq * 72;
        int zl = 256 - k0; if (zl > 72) zl = 72;
        const int alen = zl >> 2;
        const float* actA = smem + ZX + b * 260 + k0;
        const float* actB = smem + H3F + b * 40 + (k0 + (alen << 2) - 256);
        const int s0 = k0 >> 2;
        float acc0 = 0.f, acc1 = 0.f, acc2 = 0.f, acc3 = 0.f;
        #pragma unroll 2
        for (int i = 0; i < 18; ++i) {
            const float* ap = (i < alen) ? (actA + 4 * i) : (actB + 4 * (i - alen));
            const float4 a = *(const float4*)ap;
            const int sl = s0 + i;
            {   const int r = 0 * 8 + ch;
                const float4 w = *(const float4*)(smem + WST + (r * 72 + (sl ^ (r & 7))) * 4);
                acc0 += dot4(w, a); }
            {   const int r = 1 * 8 + ch;
                const float4 w = *(const float4*)(smem + WST + (r * 72 + (sl ^ (r & 7))) * 4);
                acc1 += dot4(w, a); }
            {   const int r = 2 * 8 + ch;
                const float4 w = *(const float4*)(smem + WST + (r * 72 + (sl ^ (r & 7))) * 4);
                acc2 += dot4(w, a); }
            {   const int r = 3 * 8 + ch;
                const float4 w = *(const float4*)(smem + WST + (r * 72 + (sl ^ (r & 7))) * 4);
                acc3 += dot4(w, a); }
        }
        smem[G3BUF + (kq * 32 + 0 * 8 + ch) * 16 + b] = acc0;
        smem[G3BUF + (kq * 32 + 1 * 8 + ch) * 16 + b] = acc1;
        smem[G3BUF + (kq * 32 + 2 * 8 + ch) * 16 + b] = acc2;
        smem[G3BUF + (kq * 32 + 3 * 8 + ch) * 16 + b] = acc3;
    };

    auto point3 = [&](int tstep) {
        const int ch = tid >> 4;    // 0..7 (tid < 128)
        const int b = tid & 15;
        float gg[4];
        #pragma unroll
        for (int g = 0; g < 4; ++g) {
            float s = smem[SB3 + ch * 4 + g];
            #pragma unroll
            for (int kq = 0; kq < 4; ++kq)
                s += smem[G3BUF + (kq * 32 + g * 8 + ch) * 16 + b];
            gg[g] = s;
        }
        float* cp = smem + C3O + ch * 16 + b;
        float c = *cp;
        const float h = lstm_point(gg[0], gg[1], gg[2], gg[3], c);
        *cp = c;
        ws[WS_H3X + (size_t)(CQ * 8 + ch) * B + BG * 16 + b] = h;
        float s = h, q = h * h;
        #pragma unroll
        for (int off = 1; off < 16; off <<= 1) {
            s += __shfl_xor(s, off, 64);
            q += __shfl_xor(q, off, 64);
        }
        if (b == 0) {
            float* st = ws + WS_ST + (size_t)tstep * 1088 + 1024 + (size_t)(CQ * 8 + ch) * 2;
            atomicAdd(st, s);
            atomicAdd(st + 1, q);
        }
    };

    // ---- BN3 + linear head + softmax for this block's 16 rows (tid < 16) ----
    auto head = [&](int tt) {
        const int b = tid;
        float y0 = smem[SWH + 68], y1 = smem[SWH + 69];
        #pragma unroll 8
        for (int ch = 0; ch < 32; ++ch) {
            const float z = smem[SA + ch] * smem[H3F + b * 40 + ch] + smem[SD + ch];
            y0 += smem[SWH + ch] * z;
            y1 += smem[SWH + 32 + ch] * z;
        }
        y0 = fmaxf(y0, 0.f); y1 = fmaxf(y1, 0.f);
        const float u0 = smem[SWH + 64] * y0 + smem[SWH + 65] * y1 + smem[SWH + 70];
        const float u1 = smem[SWH + 66] * y0 + smem[SWH + 67] * y1 + smem[SWH + 71];
        const float m = fmaxf(u0, u1);
        const float e0 = __expf(u0 - m), e1 = __expf(u1 - m);
        const float inv = 1.f / (e0 + e1);
        *(float2*)&out[((size_t)(BG * 16 + b) * T + tt) * 2] = make_float2(e0 * inv, e1 * inv);
    };

    // ================= init =================
    for (int i = blk * NTHR + tid; i < T * 1088; i += NBLK * NTHR) ws[WS_ST + i] = 0.f;
    for (int i = tid; i < 4160; i += NTHR) { smem[H1F + i] = 0.f; smem[H2F + i] = 0.f; }
    for (int i = tid; i < 1024; i += NTHR) { smem[C1O + i] = 0.f; smem[C2O + i] = 0.f; }
    if (tid < 128) smem[C3O + tid] = 0.f;
    if (tid < 256) {
        const int g = tid >> 6, cl = tid & 63;
        const int j = g * 256 + CQ * 64 + cl;
        smem[SB1 + cl * 4 + g] = bih1[j] + bhh1[j];
    } else {
        const int t2 = tid - 256;
        const int g = t2 >> 6, cl = t2 & 63;
        const int j = g * 256 + CQ * 64 + cl;
        smem[SB2 + cl * 4 + g] = bih2[j] + bhh2[j];
    }
    if (tid < 32) {
        const int g = tid >> 3, cl = tid & 7;
        const int j = g * 32 + CQ * 8 + cl;
        smem[SB3 + cl * 4 + g] = bih3[j] + bhh3[j];
    }
    if (tid >= 64 && tid < 136) {
        const int i = tid - 64;
        float v;
        if (i < 64) v = Wl[i];
        else if (i < 68) v = Wl2[i - 64];
        else if (i < 70) v = bl[i - 68];
        else v = bl2[i - 70];
        smem[SWH + i] = v;
    }
    grid.sync();

    // ================= time loop =================
    for (int t = 0; t < T; ++t) {
        // ---------- Phase 1: head(t-1) + L1(t) ----------
        stage12(0, 0, 1);
        {   // stage x rows into xrow (ZX alias, pitch 132)
            const int row = tid >> 5, kq4 = tid & 31;
            const float4 v = *(const float4*)&x[(((size_t)(BG * 16 + row)) * T + t) * 128 + kq4 * 4];
            *(float4*)&smem[ZX + row * 132 + kq4 * 4] = v;
        }
        {   // assemble h3(t-1) full (b-major pitch 40)
            const int ch = tid >> 4, b = tid & 15;
            smem[H3F + b * 40 + ch] =
                (t == 0) ? 0.f : ws[WS_H3X + (size_t)ch * B + BG * 16 + b];
        }
        if (CQ == 0 && t > 0)
            bn_ad(ws + WS_ST + (size_t)(t - 1) * 1088 + 1024, g3v, b3v, 32);
        __syncthreads();
        if (CQ == 0 && t > 0 && tid < 16) head(t - 1);

        for (int ci = 0; ci < 16; ++ci) {
            if (ci < 15) stage12(ci + 1, (ci + 1) & 1, 1);
            compute12(ci, ci & 1, 1);
            __syncthreads();
            if (tid < 64) point12(ci, ci & 1, 1, t);
        }
        grid.sync();

        // ---------- Phase 2: BN1 (folded) + L2(t) ----------
        stage12(0, 0, 2);
        bn_ad(ws + WS_ST + (size_t)t * 1088, g1v, b1v, 256);
        __syncthreads();
        assemble(ws + WS_H1X, H1F);
        __syncthreads();
        for (int ci = 0; ci < 16; ++ci) {
            if (ci < 15) stage12(ci + 1, (ci + 1) & 1, 2);
            compute12(ci, ci & 1, 2);
            __syncthreads();
            if (tid < 64) point12(ci, ci & 1, 2, t);
        }
        grid.sync();

        // ---------- Phase 3: BN2 (folded) + L3(t) ----------
        stage3();
        bn_ad(ws + WS_ST + (size_t)t * 1088 + 512, g2v, b2v, 256);
        __syncthreads();
        assemble(ws + WS_H2X, H2F);
        __syncthreads();
        compute3();
        __syncthreads();
        if (tid < 128) point3(t);
        grid.sync();
    }

    // ================= epilogue: head for t = T-1 =================
    if (CQ == 0) {
        const int ch = tid >> 4, b = tid & 15;
        smem[H3F + b * 40 + ch] = ws[WS_H3X + (size_t)ch * B + BG * 16 + b];
        bn_ad(ws + WS_ST + (size_t)(T - 1) * 1088 + 1024, g3v, b3v, 32);
        __syncthreads();
        if (tid < 16) head(T - 1);
    }
}

extern "C" void kernel_launch(void* const* d_in, const int* in_sizes, int n_in,
                              void* d_out, int out_size, void* d_ws, size_t ws_size,
                              hipStream_t stream) {
    const float* x    = (const float*)d_in[0];
    const float* Wih1 = (const float*)d_in[1];
    const float* Whh1 = (const float*)d_in[2];
    const float* bih1 = (const float*)d_in[3];
    const float* bhh1 = (const float*)d_in[4];
    const float* g1   = (const float*)d_in[5];
    const float* b1   = (const float*)d_in[6];
    const float* Wih2 = (const float*)d_in[7];
    const float* Whh2 = (const float*)d_in[8];
    const float* bih2 = (const float*)d_in[9];
    const float* bhh2 = (const float*)d_in[10];
    const float* g2   = (const float*)d_in[11];
    const float* b2   = (const float*)d_in[12];
    const float* Wih3 = (const float*)d_in[13];
    const float* Whh3 = (const float*)d_in[14];
    const float* bih3 = (const float*)d_in[15];
    const float* bhh3 = (const float*)d_in[16];
    const float* g3   = (const float*)d_in[17];
    const float* b3   = (const float*)d_in[18];
    const float* Wl   = (const float*)d_in[19];
    const float* bl   = (const float*)d_in[20];
    const float* Wl2  = (const float*)d_in[21];
    const float* bl2  = (const float*)d_in[22];
    float* out = (float*)d_out;
    float* ws  = (float*)d_ws;

    const int dyn_lds = LDS_FLOATS * sizeof(float);   // 155,808 B
    hipFuncSetAttribute((const void*)cryptonet_kernel,
                        hipFuncAttributeMaxDynamicSharedMemorySize, dyn_lds);

    void* args[] = { &x, &Wih1, &Whh1, &bih1, &bhh1, &g1, &b1,
                     &Wih2, &Whh2, &bih2, &bhh2, &g2, &b2,
                     &Wih3, &Whh3, &bih3, &bhh3, &g3, &b3,
                     &Wl, &bl, &Wl2, &bl2, &out, &ws };
    hipLaunchCooperativeKernel((const void*)cryptonet_kernel, dim3(NBLK), dim3(NTHR),
                               args, dyn_lds, stream);
}

// Round 5
// 29294.635 us; speedup vs baseline: 1.6029x; 1.6029x over previous
//
#include <hip/hip_runtime.h>
#include <hip/hip_cooperative_groups.h>

namespace cg = cooperative_groups;

#define B    1024
#define T    256
#define NBLK 256
#define NTHR 512
#define EPS  1e-5f

typedef _Float16 f16;
typedef _Float16 f16x8 __attribute__((ext_vector_type(8)));
typedef float    f32x4 __attribute__((ext_vector_type(4)));

// ---- ws byte offsets ----
#define WS_H1X 0u            // f16 [2][1024][256]
#define WS_H2X 1048576u      // f16 [2][1024][256]
#define WS_H3X 2097152u      // f16 [2][1024][32]
#define WS_ST  2228224u      // f32 [T][1088]: st1 256*2 | st2 256*2 | st3 32*2

// ---- dynamic LDS byte offsets ----
#define OW1 0        // f16[32][392]  W1 slice, rr = g*8+c, k-contig
#define OW2 25088    // f16[32][520]
#define OW3 58368    // f16[16][296]  (rows 4..15 zero pad)
#define OAA 67840    // f32[256] BN scale a
#define ODD 68864    // f32[256] BN shift d
#define OB1 69888    // f32[32]
#define OB2 70016    // f32[32]
#define OB3 70144    // f32[4]
#define OA3 70160    // f32[32]
#define OD3 70288    // f32[32]
#define OHW 70416    // f32[72]: Wl(64) Wl2(4) bl(2) bl2(2)
#define OC1 70704    // f32[8][132]
#define OC2 74928    // f32[8][132]
#define OC3 79152    // f32[132]
#define LDSBYTES 79680

__device__ __forceinline__ float fsigmoid(float v) { return 1.f / (1.f + __expf(-v)); }
__device__ __forceinline__ float ftanh(float v)    { return 1.f - 2.f / (__expf(2.f * v) + 1.f); }

__global__ void __launch_bounds__(NTHR) cryptonet_kernel(
    const float* __restrict__ x,
    const float* __restrict__ Wih1, const float* __restrict__ Whh1,
    const float* __restrict__ bih1, const float* __restrict__ bhh1,
    const float* __restrict__ g1v,  const float* __restrict__ b1v,
    const float* __restrict__ Wih2, const float* __restrict__ Whh2,
    const float* __restrict__ bih2, const float* __restrict__ bhh2,
    const float* __restrict__ g2v,  const float* __restrict__ b2v,
    const float* __restrict__ Wih3, const float* __restrict__ Whh3,
    const float* __restrict__ bih3, const float* __restrict__ bhh3,
    const float* __restrict__ g3v,  const float* __restrict__ b3v,
    const float* __restrict__ Wl,   const float* __restrict__ bl,
    const float* __restrict__ Wl2,  const float* __restrict__ bl2,
    float* __restrict__ out, float* __restrict__ ws)
{
    cg::grid_group grid = cg::this_grid();
    const int tid  = threadIdx.x;
    const int blk  = blockIdx.x;
    const int CG   = blk >> 3;        // 0..31 channel group (8 ch of H1/H2, 1 ch of H3)
    const int BGr  = blk & 7;         // 0..7 batch group (XCD = blk%8 = BGr -> same-XCD exchange)
    const int b0   = BGr * 128;
    const int wv   = tid >> 6;        // wave = m-tile 0..7
    const int lane = tid & 63;
    const int q    = lane >> 4;       // quad
    const int mlo  = lane & 15;

    extern __shared__ char smraw[];
    f16*   w1  = (f16*)(smraw + OW1);
    f16*   w2  = (f16*)(smraw + OW2);
    f16*   w3  = (f16*)(smraw + OW3);
    float* sA  = (float*)(smraw + OAA);
    float* sD  = (float*)(smraw + ODD);
    float* sB1 = (float*)(smraw + OB1);
    float* sB2 = (float*)(smraw + OB2);
    float* sB3 = (float*)(smraw + OB3);
    float* sA3 = (float*)(smraw + OA3);
    float* sD3 = (float*)(smraw + OD3);
    float* sHW = (float*)(smraw + OHW);
    float* c1  = (float*)(smraw + OC1);
    float* c2  = (float*)(smraw + OC2);
    float* c3  = (float*)(smraw + OC3);

    char* ws8 = (char*)ws;
    f16*   h1x   = (f16*)(ws8 + WS_H1X);   // [2][1024][256]
    f16*   h2x   = (f16*)(ws8 + WS_H2X);
    f16*   h3x   = (f16*)(ws8 + WS_H3X);   // [2][1024][32]
    float* stats = (float*)(ws8 + WS_ST);  // [T][1088]

    // ================= init: weights -> LDS (fp16), biases, zero state =================
    for (int idx = tid; idx < 32 * 384; idx += NTHR) {
        const int rr = idx / 384, k = idx - rr * 384;
        const int j = (rr >> 3) * 256 + CG * 8 + (rr & 7);
        const float v = (k < 128) ? Wih1[(size_t)j * 128 + k] : Whh1[(size_t)j * 256 + (k - 128)];
        w1[rr * 392 + k] = (f16)v;
    }
    for (int idx = tid; idx < 32 * 512; idx += NTHR) {
        const int rr = idx >> 9, k = idx & 511;
        const int j = (rr >> 3) * 256 + CG * 8 + (rr & 7);
        const float v = (k < 256) ? Wih2[(size_t)j * 256 + k] : Whh2[(size_t)j * 256 + (k - 256)];
        w2[rr * 520 + k] = (f16)v;
    }
    for (int idx = tid; idx < 16 * 296; idx += NTHR) w3[idx] = (f16)0.f;
    __syncthreads();
    for (int idx = tid; idx < 4 * 288; idx += NTHR) {
        const int rr = idx / 288, k = idx - rr * 288;  // rr = gate g
        const int j = rr * 32 + CG;
        const float v = (k < 256) ? Wih3[(size_t)j * 256 + k] : Whh3[(size_t)j * 32 + (k - 256)];
        w3[rr * 296 + k] = (f16)v;
    }
    if (tid < 32) {
        const int j = (tid >> 3) * 256 + CG * 8 + (tid & 7);
        sB1[tid] = bih1[j] + bhh1[j];
        const int j2 = (tid >> 3) * 256 + CG * 8 + (tid & 7);
        sB2[tid] = bih2[j2] + bhh2[j2];
    }
    if (tid >= 32 && tid < 36) {
        const int g = tid - 32;
        sB3[g] = bih3[g * 32 + CG] + bhh3[g * 32 + CG];
    }
    if (tid >= 64 && tid < 136) {
        const int i = tid - 64;
        float v;
        if (i < 64) v = Wl[i];
        else if (i < 68) v = Wl2[i - 64];
        else if (i < 70) v = bl[i - 68];
        else v = bl2[i - 70];
        sHW[i] = v;
    }
    for (int i = tid; i < 8 * 132; i += NTHR) { c1[i] = 0.f; c2[i] = 0.f; }
    if (tid < 132) c3[tid] = 0.f;
    // zero global: H1X[0], H2X[0], H3X[0], stats (ws poisoned 0xAA each call)
    {
        unsigned int* z1 = (unsigned int*)h1x;
        unsigned int* z2 = (unsigned int*)h2x;
        unsigned int* z3 = (unsigned int*)h3x;
        unsigned int* zs = (unsigned int*)stats;
        const int gt = blk * NTHR + tid, gs = NBLK * NTHR;
        for (int i = gt; i < 131072; i += gs) z1[i] = 0u;   // 512 KB
        for (int i = gt; i < 131072; i += gs) z2[i] = 0u;
        for (int i = gt; i < 16384;  i += gs) z3[i] = 0u;   // 64 KB
        for (int i = gt; i < T * 1088; i += gs) zs[i] = 0u;
    }
    grid.sync();

    // pointwise for phases 1/2 (8 ch per block): gates land as
    // lane n<8: acc0 = i-gate, acc1 = g-gate; lane n+8: acc0 = f, acc1 = o.
    auto pointwise12 = [&](float* cst, f16* hdst, float* statp, const float* bias,
                           f32x4 acc0, f32x4 acc1) {
        float fr[4], orr[4];
        #pragma unroll
        for (int r = 0; r < 4; ++r) {
            fr[r]  = __shfl_xor(acc0[r], 8);
            orr[r] = __shfl_xor(acc1[r], 8);
        }
        float s = 0.f, sq = 0.f;
        const int c = mlo & 7;
        if (mlo < 8) {
            const float bi = bias[c], bf = bias[8 + c], bg = bias[16 + c], bo = bias[24 + c];
            float4 cc = *(float4*)&cst[c * 132 + wv * 16 + q * 4];
            float cv[4] = {cc.x, cc.y, cc.z, cc.w};
            #pragma unroll
            for (int r = 0; r < 4; ++r) {
                const float gi = fsigmoid(acc0[r] + bi);
                const float gf = fsigmoid(fr[r] + bf);
                const float gg = ftanh(acc1[r] + bg);
                const float go = fsigmoid(orr[r] + bo);
                const float cn = gf * cv[r] + gi * gg;
                cv[r] = cn;
                const f16 h16 = (f16)(go * ftanh(cn));
                hdst[(size_t)(b0 + wv * 16 + q * 4 + r) * 256 + CG * 8 + c] = h16;
                const float hq = (float)h16;
                s += hq; sq += hq * hq;
            }
            *(float4*)&cst[c * 132 + wv * 16 + q * 4] = make_float4(cv[0], cv[1], cv[2], cv[3]);
        }
        s  += __shfl_xor(s, 16);  s  += __shfl_xor(s, 32);
        sq += __shfl_xor(sq, 16); sq += __shfl_xor(sq, 32);
        if (mlo < 8 && q == 0) {
            atomicAdd(statp + c * 2, s);
            atomicAdd(statp + c * 2 + 1, sq);
        }
    };

    // ================= time loop =================
    for (int t = 0; t < T; ++t) {
        const int par = t & 1;
        const f16* h1p = h1x + (size_t)par * B * 256;
        f16*       h1c = h1x + (size_t)(par ^ 1) * B * 256;
        const f16* h2p = h2x + (size_t)par * B * 256;
        f16*       h2c = h2x + (size_t)(par ^ 1) * B * 256;
        const f16* h3p = h3x + (size_t)par * B * 32;
        f16*       h3c = h3x + (size_t)(par ^ 1) * B * 32;

        // ---------- Phase 1: head(t-1) [CG==0] + L1(t) ----------
        if (CG == 0 && t > 0) {
            if (tid < 32) {
                const float s  = stats[(size_t)(t - 1) * 1088 + 1024 + tid * 2];
                const float qq = stats[(size_t)(t - 1) * 1088 + 1024 + tid * 2 + 1];
                const float mu = s * (1.f / B);
                const float var = qq * (1.f / B) - mu * mu;
                const float a = g3v[tid] * rsqrtf(var + EPS);
                sA3[tid] = a; sD3[tid] = b3v[tid] - mu * a;
            }
            __syncthreads();
            if (lane < 16) {
                const int b = b0 + wv * 16 + lane;
                const f16* hp = h3p + (size_t)b * 32;
                float y0 = sHW[68], y1 = sHW[69];
                #pragma unroll 8
                for (int ch = 0; ch < 32; ++ch) {
                    const float z = sA3[ch] * (float)hp[ch] + sD3[ch];
                    y0 += sHW[ch] * z; y1 += sHW[32 + ch] * z;
                }
                y0 = fmaxf(y0, 0.f); y1 = fmaxf(y1, 0.f);
                const float u0 = sHW[64] * y0 + sHW[65] * y1 + sHW[70];
                const float u1 = sHW[66] * y0 + sHW[67] * y1 + sHW[71];
                const float m = fmaxf(u0, u1);
                const float e0 = __expf(u0 - m), e1 = __expf(u1 - m);
                const float inv = 1.f / (e0 + e1);
                *(float2*)&out[((size_t)b * T + (t - 1)) * 2] = make_float2(e0 * inv, e1 * inv);
            }
        }
        {
            const int brow = b0 + wv * 16 + mlo;
            f16x8 af[12];
            #pragma unroll
            for (int kt = 0; kt < 4; ++kt) {   // x part, fp32 -> fp16
                const float* xp = x + ((size_t)brow * T + t) * 128 + kt * 32 + q * 8;
                const float4 u = *(const float4*)xp;
                const float4 v = *(const float4*)(xp + 4);
                f16x8 a;
                a[0] = (f16)u.x; a[1] = (f16)u.y; a[2] = (f16)u.z; a[3] = (f16)u.w;
                a[4] = (f16)v.x; a[5] = (f16)v.y; a[6] = (f16)v.z; a[7] = (f16)v.w;
                af[kt] = a;
            }
            #pragma unroll
            for (int kt = 4; kt < 12; ++kt)    // h1(t-1) raw
                af[kt] = *(const f16x8*)(h1p + (size_t)brow * 256 + (kt - 4) * 32 + q * 8);
            f32x4 acc0 = {0.f, 0.f, 0.f, 0.f}, acc1 = {0.f, 0.f, 0.f, 0.f};
            #pragma unroll
            for (int kt = 0; kt < 12; ++kt) {
                const f16x8 bf0 = *(const f16x8*)(w1 + mlo * 392 + kt * 32 + q * 8);
                const f16x8 bf1 = *(const f16x8*)(w1 + (16 + mlo) * 392 + kt * 32 + q * 8);
                acc0 = __builtin_amdgcn_mfma_f32_16x16x32_f16(af[kt], bf0, acc0, 0, 0, 0);
                acc1 = __builtin_amdgcn_mfma_f32_16x16x32_f16(af[kt], bf1, acc1, 0, 0, 0);
            }
            pointwise12(c1, h1c, stats + (size_t)t * 1088 + CG * 16, sB1, acc0, acc1);
        }
        grid.sync();

        // ---------- Phase 2: BN1 (folded into A-frags) + L2(t) ----------
        if (tid < 256) {
            const float s  = stats[(size_t)t * 1088 + tid * 2];
            const float qq = stats[(size_t)t * 1088 + tid * 2 + 1];
            const float mu = s * (1.f / B);
            const float var = qq * (1.f / B) - mu * mu;
            const float a = g1v[tid] * rsqrtf(var + EPS);
            sA[tid] = a; sD[tid] = b1v[tid] - mu * a;
        }
        __syncthreads();
        {
            const int brow = b0 + wv * 16 + mlo;
            f16x8 af[16];
            #pragma unroll
            for (int kt = 0; kt < 8; ++kt)
                af[kt] = *(const f16x8*)(h1c + (size_t)brow * 256 + kt * 32 + q * 8);
            #pragma unroll
            for (int kt = 8; kt < 16; ++kt)
                af[kt] = *(const f16x8*)(h2p + (size_t)brow * 256 + (kt - 8) * 32 + q * 8);
            #pragma unroll
            for (int kt = 0; kt < 8; ++kt) {   // fold z1 = a*h1 + d
                const int k = kt * 32 + q * 8;
                const float4 aa0 = *(const float4*)&sA[k];
                const float4 aa1 = *(const float4*)&sA[k + 4];
                const float4 dd0 = *(const float4*)&sD[k];
                const float4 dd1 = *(const float4*)&sD[k + 4];
                f16x8 a = af[kt];
                a[0] = (f16)(aa0.x * (float)a[0] + dd0.x);
                a[1] = (f16)(aa0.y * (float)a[1] + dd0.y);
                a[2] = (f16)(aa0.z * (float)a[2] + dd0.z);
                a[3] = (f16)(aa0.w * (float)a[3] + dd0.w);
                a[4] = (f16)(aa1.x * (float)a[4] + dd1.x);
                a[5] = (f16)(aa1.y * (float)a[5] + dd1.y);
                a[6] = (f16)(aa1.z * (float)a[6] + dd1.z);
                a[7] = (f16)(aa1.w * (float)a[7] + dd1.w);
                af[kt] = a;
            }
            f32x4 acc0 = {0.f, 0.f, 0.f, 0.f}, acc1 = {0.f, 0.f, 0.f, 0.f};
            #pragma unroll
            for (int kt = 0; kt < 16; ++kt) {
                const f16x8 bf0 = *(const f16x8*)(w2 + mlo * 520 + kt * 32 + q * 8);
                const f16x8 bf1 = *(const f16x8*)(w2 + (16 + mlo) * 520 + kt * 32 + q * 8);
                acc0 = __builtin_amdgcn_mfma_f32_16x16x32_f16(af[kt], bf0, acc0, 0, 0, 0);
                acc1 = __builtin_amdgcn_mfma_f32_16x16x32_f16(af[kt], bf1, acc1, 0, 0, 0);
            }
            pointwise12(c2, h2c, stats + (size_t)t * 1088 + 512 + CG * 16, sB2, acc0, acc1);
        }
        grid.sync();

        // ---------- Phase 3: BN2 (folded) + L3(t) ----------
        if (tid < 256) {
            const float s  = stats[(size_t)t * 1088 + 512 + tid * 2];
            const float qq = stats[(size_t)t * 1088 + 512 + tid * 2 + 1];
            const float mu = s * (1.f / B);
            const float var = qq * (1.f / B) - mu * mu;
            const float a = g2v[tid] * rsqrtf(var + EPS);
            sA[tid] = a; sD[tid] = b2v[tid] - mu * a;
        }
        __syncthreads();
        {
            const int brow = b0 + wv * 16 + mlo;
            f16x8 af[9];
            #pragma unroll
            for (int kt = 0; kt < 8; ++kt)
                af[kt] = *(const f16x8*)(h2c + (size_t)brow * 256 + kt * 32 + q * 8);
            af[8] = *(const f16x8*)(h3p + (size_t)brow * 32 + q * 8);
            #pragma unroll
            for (int kt = 0; kt < 8; ++kt) {   // fold z2
                const int k = kt * 32 + q * 8;
                const float4 aa0 = *(const float4*)&sA[k];
                const float4 aa1 = *(const float4*)&sA[k + 4];
                const float4 dd0 = *(const float4*)&sD[k];
                const float4 dd1 = *(const float4*)&sD[k + 4];
                f16x8 a = af[kt];
                a[0] = (f16)(aa0.x * (float)a[0] + dd0.x);
                a[1] = (f16)(aa0.y * (float)a[1] + dd0.y);
                a[2] = (f16)(aa0.z * (float)a[2] + dd0.z);
                a[3] = (f16)(aa0.w * (float)a[3] + dd0.w);
                a[4] = (f16)(aa1.x * (float)a[4] + dd1.x);
                a[5] = (f16)(aa1.y * (float)a[5] + dd1.y);
                a[6] = (f16)(aa1.z * (float)a[6] + dd1.z);
                a[7] = (f16)(aa1.w * (float)a[7] + dd1.w);
                af[kt] = a;
            }
            f32x4 acc0 = {0.f, 0.f, 0.f, 0.f};
            #pragma unroll
            for (int kt = 0; kt < 9; ++kt) {
                const f16x8 bf0 = *(const f16x8*)(w3 + mlo * 296 + kt * 32 + q * 8);
                acc0 = __builtin_amdgcn_mfma_f32_16x16x32_f16(af[kt], bf0, acc0, 0, 0, 0);
            }
            // gather 4 gates (rows rr = g) from lanes q*16+g
            float gi[4], gf_[4], gg_[4], go_[4];
            #pragma unroll
            for (int r = 0; r < 4; ++r) {
                gi[r]  = __shfl(acc0[r], (lane & 48) + 0);
                gf_[r] = __shfl(acc0[r], (lane & 48) + 1);
                gg_[r] = __shfl(acc0[r], (lane & 48) + 2);
                go_[r] = __shfl(acc0[r], (lane & 48) + 3);
            }
            float s = 0.f, sq = 0.f;
            if (mlo == 0) {
                float4 cc = *(float4*)&c3[wv * 16 + q * 4];
                float cv[4] = {cc.x, cc.y, cc.z, cc.w};
                #pragma unroll
                for (int r = 0; r < 4; ++r) {
                    const float i_ = fsigmoid(gi[r] + sB3[0]);
                    const float f_ = fsigmoid(gf_[r] + sB3[1]);
                    const float g_ = ftanh(gg_[r] + sB3[2]);
                    const float o_ = fsigmoid(go_[r] + sB3[3]);
                    const float cn = f_ * cv[r] + i_ * g_;
                    cv[r] = cn;
                    const f16 h16 = (f16)(o_ * ftanh(cn));
                    h3c[(size_t)(b0 + wv * 16 + q * 4 + r) * 32 + CG] = h16;
                    const float hq = (float)h16;
                    s += hq; sq += hq * hq;
                }
                *(float4*)&c3[wv * 16 + q * 4] = make_float4(cv[0], cv[1], cv[2], cv[3]);
            }
            s  += __shfl_xor(s, 16);  s  += __shfl_xor(s, 32);
            sq += __shfl_xor(sq, 16); sq += __shfl_xor(sq, 32);
            if (lane == 0) {
                atomicAdd(&stats[(size_t)t * 1088 + 1024 + CG * 2], s);
                atomicAdd(&stats[(size_t)t * 1088 + 1024 + CG * 2 + 1], sq);
            }
        }
        grid.sync();
    }

    // ================= epilogue: head for t = T-1 =================
    if (CG == 0) {
        const f16* h3s = h3x + (size_t)((T - 1) & 1 ? 0 : 1) * B * 32;  // written to par^1 of t=255 -> [0]
        if (tid < 32) {
            const float s  = stats[(size_t)(T - 1) * 1088 + 1024 + tid * 2];
            const float qq = stats[(size_t)(T - 1) * 1088 + 1024 + tid * 2 + 1];
            const float mu = s * (1.f / B);
            const float var = qq * (1.f / B) - mu * mu;
            const float a = g3v[tid] * rsqrtf(var + EPS);
            sA3[tid] = a; sD3[tid] = b3v[tid] - mu * a;
        }
        __syncthreads();
        if (lane < 16) {
            const int b = b0 + wv * 16 + lane;
            const f16* hp = h3s + (size_t)b * 32;
            float y0 = sHW[68], y1 = sHW[69];
            #pragma unroll 8
            for (int ch = 0; ch < 32; ++ch) {
                const float z = sA3[ch] * (float)hp[ch] + sD3[ch];
                y0 += sHW[ch] * z; y1 += sHW[32 + ch] * z;
            }
            y0 = fmaxf(y0, 0.f); y1 = fmaxf(y1, 0.f);
            const float u0 = sHW[64] * y0 + sHW[65] * y1 + sHW[70];
            const float u1 = sHW[66] * y0 + sHW[67] * y1 + sHW[71];
            const float m = fmaxf(u0, u1);
            const float e0 = __expf(u0 - m), e1 = __expf(u1 - m);
            const float inv = 1.f / (e0 + e1);
            *(float2*)&out[((size_t)b * T + (T - 1)) * 2] = make_float2(e0 * inv, e1 * inv);
        }
    }
}

extern "C" void kernel_launch(void* const* d_in, const int* in_sizes, int n_in,
                              void* d_out, int out_size, void* d_ws, size_t ws_size,
                              hipStream_t stream) {
    const float* x    = (const float*)d_in[0];
    const float* Wih1 = (const float*)d_in[1];
    const float* Whh1 = (const float*)d_in[2];
    const float* bih1 = (const float*)d_in[3];
    const float* bhh1 = (const float*)d_in[4];
    const float* g1   = (const float*)d_in[5];
    const float* b1   = (const float*)d_in[6];
    const float* Wih2 = (const float*)d_in[7];
    const float* Whh2 = (const float*)d_in[8];
    const float* bih2 = (const float*)d_in[9];
    const float* bhh2 = (const float*)d_in[10];
    const float* g2   = (const float*)d_in[11];
    const float* b2   = (const float*)d_in[12];
    const float* Wih3 = (const float*)d_in[13];
    const float* Whh3 = (const float*)d_in[14];
    const float* bih3 = (const float*)d_in[15];
    const float* bhh3 = (const float*)d_in[16];
    const float* g3   = (const float*)d_in[17];
    const float* b3   = (const float*)d_in[18];
    const float* Wl   = (const float*)d_in[19];
    const float* bl   = (const float*)d_in[20];
    const float* Wl2  = (const float*)d_in[21];
    const float* bl2  = (const float*)d_in[22];
    float* out = (float*)d_out;
    float* ws  = (float*)d_ws;

    const int dyn_lds = LDSBYTES;
    hipFuncSetAttribute((const void*)cryptonet_kernel,
                        hipFuncAttributeMaxDynamicSharedMemorySize, dyn_lds);

    void* args[] = { &x, &Wih1, &Whh1, &bih1, &bhh1, &g1, &b1,
                     &Wih2, &Whh2, &bih2, &bhh2, &g2, &b2,
                     &Wih3, &Whh3, &bih3, &bhh3, &g3, &b3,
                     &Wl, &bl, &Wl2, &bl2, &out, &ws };
    hipLaunchCooperativeKernel((const void*)cryptonet_kernel, dim3(NBLK), dim3(NTHR),
                               args, dyn_lds, stream);
}